// Round 7
// baseline (413.652 us; speedup 1.0000x reference)
//
#include <hip/hip_runtime.h>

typedef __attribute__((ext_vector_type(8))) short bf16x8;
typedef __attribute__((ext_vector_type(4))) float f32x4;
typedef __attribute__((ext_vector_type(4))) unsigned short u16x4;

#define GAS(p) ((const __attribute__((address_space(1))) void*)(p))
#define LAS(p) ((__attribute__((address_space(3))) void*)(p))

__device__ __forceinline__ unsigned short f2bf(float f) {
  unsigned int u = __float_as_uint(f);
  u += 0x7fffu + ((u >> 16) & 1u);
  return (unsigned short)(u >> 16);
}

__device__ __forceinline__ float bf2f(unsigned short u) {
  return __uint_as_float(((unsigned int)u) << 16);
}

__device__ __forceinline__ float fexp2(float x) {
  float r;
  asm("v_exp_f32 %0, %1" : "=v"(r) : "v"(x));
  return r;
}

// ---------------- fused f32 -> bf16 convert (all 7 tensors, 1 launch) ----------------
struct CvtArgs {
  const float *x, *wq, *wk, *wv, *wo, *w1, *w2;
  unsigned short *xb, *wqd, *wkd, *wvd, *wod, *w1d, *w2d;
};
__global__ __launch_bounds__(256) void k_convall(CvtArgs a) {
  long i = (long)blockIdx.x * 256 + threadIdx.x;  // vec4 index
  const float* s;
  unsigned short* d;
  long j;
  if (i < 1048576)      { s = a.x;  d = a.xb;  j = i; }
  else if (i < 1310720) { s = a.wq; d = a.wqd; j = i - 1048576; }
  else if (i < 1572864) { s = a.wk; d = a.wkd; j = i - 1310720; }
  else if (i < 1835008) { s = a.wv; d = a.wvd; j = i - 1572864; }
  else if (i < 2097152) { s = a.wo; d = a.wod; j = i - 1835008; }
  else if (i < 2621440) { s = a.w1; d = a.w1d; j = i - 2097152; }
  else                  { s = a.w2; d = a.w2d; j = i - 2621440; }
  f32x4 v = *(const f32x4*)(s + j * 4);
  u16x4 o;
  o[0] = f2bf(v[0]); o[1] = f2bf(v[1]); o[2] = f2bf(v[2]); o[3] = f2bf(v[3]);
  *(u16x4*)(d + j * 4) = o;
}

// ---------------- bf16 GEMM: C[M,N] = A[M,K] * B[N,K]^T ------------------------------
// OUTMODE: 0 = f32 (+bias, relu opt), 1 = bf16, 2 = bf16 TRANSPOSED (C_t[n][m], ldc=M),
//          3 = QKV router: cols [0,1024)->C, [1024,2048)->C2, [2048,3072)->C3 transposed.
template<int RELU, int OUTMODE>
__global__ __launch_bounds__(256, 2)
void k_gemm_bt(const unsigned short* __restrict__ A, const unsigned short* __restrict__ B,
               const float* __restrict__ bias, void* __restrict__ C,
               int M, int N, int K, int ldc,
               void* __restrict__ C2 = nullptr, void* __restrict__ C3 = nullptr)
{
  __shared__ char sA[128 * 128];
  __shared__ char sB[128 * 128];
  const int t = threadIdx.x, wv = t >> 6, ln = t & 63;
  const int lr = ln & 15, lg = ln >> 4;
  const int m0 = blockIdx.y * 128, n0 = blockIdx.x * 128;
  const int wm = wv >> 1, wn = wv & 1;
  f32x4 acc[4][4] = {};
  for (int k0 = 0; k0 < K; k0 += 64) {
#pragma unroll
    for (int it = 0; it < 4; ++it) {
      int p = ((it * 4 + wv) << 10) | (ln << 4);
      int row = p >> 7, colb = p & 127;
      const char* ga = (const char*)A + ((size_t)(m0 + row) * K + k0) * 2 + (colb ^ ((row & 7) << 4));
      const char* gb = (const char*)B + ((size_t)(n0 + row) * K + k0) * 2 + (colb ^ ((row & 7) << 4));
      __builtin_amdgcn_global_load_lds(GAS(ga), LAS(sA + ((it * 4 + wv) << 10)), 16, 0, 0);
      __builtin_amdgcn_global_load_lds(GAS(gb), LAS(sB + ((it * 4 + wv) << 10)), 16, 0, 0);
    }
    __syncthreads();
#pragma unroll
    for (int kk = 0; kk < 2; ++kk) {
      bf16x8 af[4], bfr[4];
#pragma unroll
      for (int i = 0; i < 4; ++i) {
        int row = wm * 64 + i * 16 + lr;
        af[i] = *(const bf16x8*)(sA + row * 128 + ((kk * 64 + lg * 16) ^ ((row & 7) << 4)));
      }
#pragma unroll
      for (int j = 0; j < 4; ++j) {
        int row = wn * 64 + j * 16 + lr;
        bfr[j] = *(const bf16x8*)(sB + row * 128 + ((kk * 64 + lg * 16) ^ ((row & 7) << 4)));
      }
#pragma unroll
      for (int i = 0; i < 4; ++i)
#pragma unroll
        for (int j = 0; j < 4; ++j)
          acc[i][j] = __builtin_amdgcn_mfma_f32_16x16x32_bf16(af[i], bfr[j], acc[i][j], 0, 0, 0);
    }
    __syncthreads();
  }
#pragma unroll
  for (int i = 0; i < 4; ++i) {
    int m = m0 + wm * 64 + i * 16 + lg * 4;
#pragma unroll
    for (int j = 0; j < 4; ++j) {
      int n = n0 + wn * 64 + j * 16 + lr;
      if (OUTMODE == 3) {
        if (n0 < 1024) {
#pragma unroll
          for (int r = 0; r < 4; ++r)
            ((unsigned short*)C)[(size_t)(m + r) * 1024 + n] = f2bf(acc[i][j][r]);
        } else if (n0 < 2048) {
#pragma unroll
          for (int r = 0; r < 4; ++r)
            ((unsigned short*)C2)[(size_t)(m + r) * 1024 + (n - 1024)] = f2bf(acc[i][j][r]);
        } else {
          u16x4 o;
#pragma unroll
          for (int r = 0; r < 4; ++r) o[r] = f2bf(acc[i][j][r]);
          *(u16x4*)((unsigned short*)C3 + (size_t)(n - 2048) * 4096 + m) = o;
        }
      } else if (OUTMODE == 2) {
        u16x4 o;
#pragma unroll
        for (int r = 0; r < 4; ++r) o[r] = f2bf(acc[i][j][r]);
        *(u16x4*)((unsigned short*)C + (size_t)n * ldc + m) = o;
      } else {
        float bv = bias ? bias[n] : 0.f;
#pragma unroll
        for (int r = 0; r < 4; ++r) {
          float v = acc[i][j][r] + bv;
          if (RELU) v = fmaxf(v, 0.f);
          if (OUTMODE == 1) ((unsigned short*)C)[(size_t)(m + r) * ldc + n] = f2bf(v);
          else ((float*)C)[(size_t)(m + r) * ldc + n] = v;
        }
      }
    }
  }
}

// ---------------- fused flash attention, split-KV, 32 q-rows/wave -------------------
// grid (N/128, H, 2): block = 128 q rows x one KV-half (2048). 4 waves, each wave owns
// 32 q (2 A-frags) -> every K/V LDS fragment read feeds 2 MFMAs. K double-buffered,
// V single-buffered (staged at top, drained mid-iter after ~1500cy of QK+softmax).
// Fixed-shift softmax (C=16) => halves are additive: partial O (bf16, unnormalized)
// + partial lsum stored; combined by k_comb. 2 blocks/CU, 8 waves/CU.
__global__ __launch_bounds__(256, 2)
void k_attn(const unsigned short* __restrict__ Qb, const unsigned short* __restrict__ Kb,
            const unsigned short* __restrict__ Vtb, const float* __restrict__ Wm,
            const float* __restrict__ Cm, const float* __restrict__ bwv,
            const float* __restrict__ bcv, unsigned short* __restrict__ Opart,
            float* __restrict__ Ls)
{
  __shared__ char sK[2 * 16384];           // [buf][64 kv][128 d] bf16, xor-swizzled
  __shared__ char sV[16384];               // [128 d][64 kv] bf16, xor-swizzled
  __shared__ unsigned short sP[4][32][76]; // pitch 76: conflict-free scatter writes
  const int t = threadIdx.x, wv = t >> 6, ln = t & 63;
  const int lr = ln & 15, lg = ln >> 4;
  const int h = blockIdx.y, z = blockIdx.z;
  const int q0 = blockIdx.x * 128 + wv * 32;
  const int kvb = z * 2048;
  const float L2E = 1.4426950408889634f;
  const float scaleL = 0.08838834764831845f * L2E; // (1/sqrt(128)) * log2e
  const float bw2 = bwv[h] * L2E, bc2 = bcv[h] * L2E;
  const float CL = 16.0f * L2E;

  // Q fragments: [a-frag][k-chunk], in registers for the whole kernel
  bf16x8 qf[2][4];
#pragma unroll
  for (int a = 0; a < 2; ++a)
#pragma unroll
    for (int kk = 0; kk < 4; ++kk)
      qf[a][kk] = *(const bf16x8*)(Qb + (size_t)(q0 + a * 16 + lr) * 1024 + h * 128 + kk * 32 + lg * 8);

  // per-row graph-bias pointers (8 q-rows per lane)
  const float* wr[8];
  const float* cr[8];
#pragma unroll
  for (int a = 0; a < 2; ++a)
#pragma unroll
    for (int r = 0; r < 4; ++r) {
      size_t off = (size_t)(q0 + a * 16 + lg * 4 + r) * 4096 + lr;
      wr[a * 4 + r] = Wm + off;
      cr[a * 4 + r] = Cm + off;
    }

  f32x4 Oacc[2][8] = {};
  float lsum[2][4] = {};

  auto stageK = [&](int buf, int kv) {
#pragma unroll
    for (int it4 = 0; it4 < 4; ++it4) {
      int p = ((it4 * 4 + wv) << 10) | (ln << 4);
      int row = p >> 8, colb = p & 255;
      const char* g = (const char*)Kb + ((size_t)(kv + row) * 1024 + h * 128) * 2 + (colb ^ ((row & 7) << 4));
      __builtin_amdgcn_global_load_lds(GAS(g), LAS(sK + buf * 16384 + p), 16, 0, 0);
    }
  };
  auto stageV = [&](int kv) {
#pragma unroll
    for (int it4 = 0; it4 < 4; ++it4) {
      int p = ((it4 * 4 + wv) << 10) | (ln << 4);
      int row = p >> 7, colb = p & 127;
      const char* g = (const char*)Vtb + ((size_t)(h * 128 + row) * 4096 + kv) * 2 + (colb ^ ((row & 7) << 4));
      __builtin_amdgcn_global_load_lds(GAS(g), LAS(sV + p), 16, 0, 0);
    }
  };

  // prologue: K tile 0 of this half
  stageK(0, kvb);
  __syncthreads();

#pragma unroll 2
  for (int it = 0; it < 32; ++it) {
    const int cur = it & 1;
    const int kv0 = kvb + (it << 6);
    const char* sKc = sK + cur * 16384;

    // V(t): issue first; drained at mid-iter barrier (~1500cy of cover below)
    stageV(kv0);

    // graph-bias loads for THIS tile (consumed after QK^T)
    float wmn[2][4][4], cmn[2][4][4];
#pragma unroll
    for (int a = 0; a < 2; ++a)
#pragma unroll
      for (int j = 0; j < 4; ++j)
#pragma unroll
        for (int r = 0; r < 4; ++r) {
          wmn[a][j][r] = wr[a * 4 + r][kv0 + j * 16];
          cmn[a][j][r] = cr[a * 4 + r][kv0 + j * 16];
        }

    // K(t+1) prefetch into other buffer
    if (it < 31) stageK(cur ^ 1, kv0 + 64);

    // S = Q K^T  (4 d-ksteps x 4 kv-ntiles x 2 a-frags)
    f32x4 S[2][4] = {};
    __builtin_amdgcn_s_setprio(1);
#pragma unroll
    for (int kk = 0; kk < 4; ++kk)
#pragma unroll
      for (int j = 0; j < 4; ++j) {
        int row = j * 16 + lr;
        bf16x8 kf = *(const bf16x8*)(sKc + row * 256 + ((kk * 64 + lg * 16) ^ ((row & 7) << 4)));
        S[0][j] = __builtin_amdgcn_mfma_f32_16x16x32_bf16(qf[0][kk], kf, S[0][j], 0, 0, 0);
        S[1][j] = __builtin_amdgcn_mfma_f32_16x16x32_bf16(qf[1][kk], kf, S[1][j], 0, 0, 0);
      }
    __builtin_amdgcn_s_setprio(0);

    // softmax numerators: p = exp2(S*scaleL + bias - C); per-lane denominator
#pragma unroll
    for (int a = 0; a < 2; ++a)
#pragma unroll
      for (int j = 0; j < 4; ++j)
#pragma unroll
        for (int r = 0; r < 4; ++r) {
          float fb = fmaf(wmn[a][j][r], bw2, fmaf(cmn[a][j][r], bc2, -CL));
          float p = fexp2(fmaf(S[a][j][r], scaleL, fb));
          lsum[a][r] += p;
          sP[wv][a * 16 + lg * 4 + r][j * 16 + lr] = f2bf(p);
        }

    __syncthreads();  // V(t) staged+drained; K(t+1) also drained (enough cover)

    // O += P V   (2 kv-ksteps x 8 d-ntiles x 2 a-frags)
    __builtin_amdgcn_s_setprio(1);
#pragma unroll
    for (int k2 = 0; k2 < 2; ++k2) {
      bf16x8 pf0 = *(const bf16x8*)((const char*)sP[wv] + (size_t)lr * 152 + k2 * 64 + lg * 16);
      bf16x8 pf1 = *(const bf16x8*)((const char*)sP[wv] + (size_t)(16 + lr) * 152 + k2 * 64 + lg * 16);
#pragma unroll
      for (int n = 0; n < 8; ++n) {
        int row = n * 16 + lr;
        bf16x8 vf = *(const bf16x8*)(sV + row * 128 + ((k2 * 64 + lg * 16) ^ ((row & 7) << 4)));
        Oacc[0][n] = __builtin_amdgcn_mfma_f32_16x16x32_bf16(pf0, vf, Oacc[0][n], 0, 0, 0);
        Oacc[1][n] = __builtin_amdgcn_mfma_f32_16x16x32_bf16(pf1, vf, Oacc[1][n], 0, 0, 0);
      }
    }
    __builtin_amdgcn_s_setprio(0);

    __syncthreads();  // all sV reads done before next iteration's stageV
  }

  // partial denominator reduce across the 16 lanes of each row group
#pragma unroll
  for (int a = 0; a < 2; ++a)
#pragma unroll
    for (int r = 0; r < 4; ++r) {
#pragma unroll
      for (int msk = 1; msk < 16; msk <<= 1) lsum[a][r] += __shfl_xor(lsum[a][r], msk, 64);
    }

  // store unnormalized bf16 partial O + f32 partial lsum
  unsigned short* Op = Opart + (size_t)z * 4194304;
#pragma unroll
  for (int a = 0; a < 2; ++a)
#pragma unroll
    for (int n = 0; n < 8; ++n)
#pragma unroll
      for (int r = 0; r < 4; ++r) {
        int qg = q0 + a * 16 + lg * 4 + r;
        Op[(size_t)qg * 1024 + h * 128 + n * 16 + lr] = f2bf(Oacc[a][n][r]);
      }
  if (lr == 0) {
#pragma unroll
    for (int a = 0; a < 2; ++a)
#pragma unroll
      for (int r = 0; r < 4; ++r)
        Ls[(size_t)(z * 8 + h) * 4096 + q0 + a * 16 + lg * 4 + r] = lsum[a][r];
  }
}

// ---------------- combine split-KV partials: O = (O0+O1)/(l0+l1) (in-place safe) -----
__global__ __launch_bounds__(256)
void k_comb(const unsigned short* __restrict__ P, const float* __restrict__ Ls,
            unsigned short* __restrict__ out)
{
  const int q = blockIdx.x, t = threadIdx.x;
  const int h = t >> 5;
  float l = Ls[(size_t)h * 4096 + q] + Ls[(size_t)(8 + h) * 4096 + q];
  float inv = 1.0f / l;
  size_t o = (size_t)q * 1024 + t * 4;
  u16x4 a = *(const u16x4*)(P + o);
  u16x4 b = *(const u16x4*)(P + 4194304 + o);
  u16x4 c;
#pragma unroll
  for (int e = 0; e < 4; ++e) c[e] = f2bf((bf2f(a[e]) + bf2f(b[e])) * inv);
  *(u16x4*)(out + o) = c;
}

// ---------------- fused residual + LayerNorm (f32 out + optional bf16 out) -----------
__global__ __launch_bounds__(256, 4)
void k_ln(const float* __restrict__ resid, const float* __restrict__ delta,
          const float* __restrict__ g, const float* __restrict__ b,
          float* __restrict__ outf, unsigned short* __restrict__ outb)
{
  const int row = blockIdx.x, t = threadIdx.x;
  const float* pr = resid + (size_t)row * 1024;
  const float* pd = delta + (size_t)row * 1024;
  f32x4 a = *(const f32x4*)(pr + t * 4);
  f32x4 d = *(const f32x4*)(pd + t * 4);
  f32x4 x;
#pragma unroll
  for (int e = 0; e < 4; ++e) x[e] = a[e] + d[e];
  float s = x[0] + x[1] + x[2] + x[3];
  float ss = x[0]*x[0] + x[1]*x[1] + x[2]*x[2] + x[3]*x[3];
#pragma unroll
  for (int msk = 1; msk < 64; msk <<= 1) {
    s += __shfl_xor(s, msk, 64);
    ss += __shfl_xor(ss, msk, 64);
  }
  __shared__ float red[8];
  if ((t & 63) == 0) { red[(t >> 6) * 2] = s; red[(t >> 6) * 2 + 1] = ss; }
  __syncthreads();
  s = red[0] + red[2] + red[4] + red[6];
  ss = red[1] + red[3] + red[5] + red[7];
  float mu = s * (1.f / 1024.f);
  float var = ss * (1.f / 1024.f) - mu * mu;
  float rstd = rsqrtf(var + 1e-5f);
#pragma unroll
  for (int e = 0; e < 4; ++e) {
    int c = t * 4 + e;
    float y = (x[e] - mu) * rstd * g[c] + b[c];
    outf[(size_t)row * 1024 + c] = y;
    if (outb) outb[(size_t)row * 1024 + c] = f2bf(y);
  }
}

// ---------------- launch ----------------
extern "C" void kernel_launch(void* const* d_in, const int* in_sizes, int n_in,
                              void* d_out, int out_size, void* d_ws, size_t ws_size,
                              hipStream_t stream) {
  const float* x   = (const float*)d_in[0];
  const float* Wm  = (const float*)d_in[1];
  const float* Cm  = (const float*)d_in[2];
  const float* Wq  = (const float*)d_in[3];
  const float* Wk  = (const float*)d_in[4];
  const float* Wv  = (const float*)d_in[5];
  const float* Wo  = (const float*)d_in[6];
  const float* bo  = (const float*)d_in[7];
  const float* bw  = (const float*)d_in[8];
  const float* bc  = (const float*)d_in[9];
  const float* g1  = (const float*)d_in[10];
  const float* be1 = (const float*)d_in[11];
  const float* g2  = (const float*)d_in[12];
  const float* be2 = (const float*)d_in[13];
  const float* W1  = (const float*)d_in[14];
  const float* b1  = (const float*)d_in[15];
  const float* W2  = (const float*)d_in[16];
  const float* b2  = (const float*)d_in[17];

  char* ws = (char*)d_ws;
  const size_t MB = 1u << 20;
  unsigned short* xb   = (unsigned short*)(ws);            // 8MB  (later reused as x1b)
  unsigned short* Wqkv = (unsigned short*)(ws + 8  * MB);  // 6MB stacked [3072][1024]
  unsigned short* Wob  = (unsigned short*)(ws + 14 * MB);  // 2MB
  unsigned short* W1b  = (unsigned short*)(ws + 16 * MB);  // 4MB
  unsigned short* W2b  = (unsigned short*)(ws + 20 * MB);  // 4MB
  unsigned short* Qb   = (unsigned short*)(ws + 24 * MB);  // 8MB
  unsigned short* Kb   = (unsigned short*)(ws + 32 * MB);  // 8MB
  unsigned short* Vtb  = (unsigned short*)(ws + 40 * MB);  // 8MB, V TRANSPOSED [1024][4096]
  unsigned short* Obuf = (unsigned short*)(ws + 48 * MB);  // 16MB as Opart[2][4096][1024];
                                                           // combined in-place into first 8MB
  float*          Lsb  = (float*)(ws + 64 * MB);           // 256KB lsum partials
  float*          tmp  = (float*)(ws + 56 * MB);           // 16MB (Wo out, then FF2 out)
                                                           //   clobbers Opart[1]+Ls (dead)
  float*          x1f  = (float*)(ws + 24 * MB);           // 16MB (over Qb/Kb, dead by then)
  unsigned short* x1b  = (unsigned short*)(ws);            // over xb (dead)
  unsigned short* hb   = (unsigned short*)(ws + 40 * MB);  // 16MB (over Vtb/Obuf, dead)

  // 1. all bf16 conversions in ONE launch (Wq/Wk/Wv stacked into Wqkv)
  CvtArgs ca;
  ca.x = x; ca.wq = Wq; ca.wk = Wk; ca.wv = Wv; ca.wo = Wo; ca.w1 = W1; ca.w2 = W2;
  ca.xb = xb; ca.wqd = Wqkv; ca.wkd = Wqkv + 1024 * 1024; ca.wvd = Wqkv + 2048 * 1024;
  ca.wod = Wob; ca.w1d = W1b; ca.w2d = W2b;
  k_convall<<<12288, 256, 0, stream>>>(ca);

  // 2. fused QKV projection: cols 0-1023 -> Qb, 1024-2047 -> Kb, 2048-3071 -> Vt^T
  k_gemm_bt<0,3><<<dim3(24, 32), 256, 0, stream>>>(xb, Wqkv, nullptr, Qb,
                                                   4096, 3072, 1024, 1024, Kb, Vtb);

  // 3. fused attention, split-KV (z = 2 halves), then combine
  k_attn<<<dim3(32, 8, 2), 256, 0, stream>>>(Qb, Kb, Vtb, Wm, Cm, bw, bc, Obuf, Lsb);
  k_comb<<<4096, 256, 0, stream>>>(Obuf, Lsb, Obuf);

  // 4. output projection (f32 out + bias)
  k_gemm_bt<0,0><<<dim3(8, 32), 256, 0, stream>>>(Obuf, Wob, bo, tmp, 4096, 1024, 1024, 1024);

  // 5. LN1: x1 = LN(x + attn_out)
  k_ln<<<4096, 256, 0, stream>>>(x, tmp, g1, be1, x1f, x1b);

  // 6. FF1 with ReLU (bf16 out)
  k_gemm_bt<1,1><<<dim3(16, 32), 256, 0, stream>>>(x1b, W1b, b1, hb, 4096, 2048, 1024, 2048);

  // 7. FF2 (f32 out)
  k_gemm_bt<0,0><<<dim3(8, 32), 256, 0, stream>>>(hb, W2b, b2, tmp, 4096, 1024, 2048, 1024);

  // 8. LN2 -> d_out
  k_ln<<<4096, 256, 0, stream>>>(x1f, tmp, g2, be2, (float*)d_out, nullptr);
}

// Round 8
// 331.864 us; speedup vs baseline: 1.2465x; 1.2465x over previous
//
#include <hip/hip_runtime.h>

typedef __attribute__((ext_vector_type(8))) short bf16x8;
typedef __attribute__((ext_vector_type(4))) float f32x4;
typedef __attribute__((ext_vector_type(4))) unsigned short u16x4;

#define GAS(p) ((const __attribute__((address_space(1))) void*)(p))
#define LAS(p) ((__attribute__((address_space(3))) void*)(p))

__device__ __forceinline__ unsigned short f2bf(float f) {
  unsigned int u = __float_as_uint(f);
  u += 0x7fffu + ((u >> 16) & 1u);
  return (unsigned short)(u >> 16);
}

__device__ __forceinline__ float bf2f(unsigned short u) {
  return __uint_as_float(((unsigned int)u) << 16);
}

__device__ __forceinline__ float fexp2(float x) {
  float r;
  asm("v_exp_f32 %0, %1" : "=v"(r) : "v"(x));
  return r;
}

// ---------------- fused f32 -> bf16 convert (all 7 tensors, 1 launch) ----------------
struct CvtArgs {
  const float *x, *wq, *wk, *wv, *wo, *w1, *w2;
  unsigned short *xb, *wqd, *wkd, *wvd, *wod, *w1d, *w2d;
};
__global__ __launch_bounds__(256) void k_convall(CvtArgs a) {
  long i = (long)blockIdx.x * 256 + threadIdx.x;  // vec4 index
  const float* s;
  unsigned short* d;
  long j;
  if (i < 1048576)      { s = a.x;  d = a.xb;  j = i; }
  else if (i < 1310720) { s = a.wq; d = a.wqd; j = i - 1048576; }
  else if (i < 1572864) { s = a.wk; d = a.wkd; j = i - 1310720; }
  else if (i < 1835008) { s = a.wv; d = a.wvd; j = i - 1572864; }
  else if (i < 2097152) { s = a.wo; d = a.wod; j = i - 1835008; }
  else if (i < 2621440) { s = a.w1; d = a.w1d; j = i - 2097152; }
  else                  { s = a.w2; d = a.w2d; j = i - 2621440; }
  f32x4 v = *(const f32x4*)(s + j * 4);
  u16x4 o;
  o[0] = f2bf(v[0]); o[1] = f2bf(v[1]); o[2] = f2bf(v[2]); o[3] = f2bf(v[3]);
  *(u16x4*)(d + j * 4) = o;
}

// ---------------- bf16 GEMM: C[M,N] = A[M,K] * B[N,K]^T ------------------------------
// OUTMODE: 0 = f32 (+bias, relu opt), 1 = bf16, 2 = bf16 TRANSPOSED (C_t[n][m], ldc=M),
//          3 = QKV router: cols [0,1024)->C, [1024,2048)->C2, [2048,3072)->C3 transposed.
template<int RELU, int OUTMODE>
__global__ __launch_bounds__(256, 2)
void k_gemm_bt(const unsigned short* __restrict__ A, const unsigned short* __restrict__ B,
               const float* __restrict__ bias, void* __restrict__ C,
               int M, int N, int K, int ldc,
               void* __restrict__ C2 = nullptr, void* __restrict__ C3 = nullptr)
{
  __shared__ char sA[128 * 128];
  __shared__ char sB[128 * 128];
  const int t = threadIdx.x, wv = t >> 6, ln = t & 63;
  const int lr = ln & 15, lg = ln >> 4;
  const int m0 = blockIdx.y * 128, n0 = blockIdx.x * 128;
  const int wm = wv >> 1, wn = wv & 1;
  f32x4 acc[4][4] = {};
  for (int k0 = 0; k0 < K; k0 += 64) {
#pragma unroll
    for (int it = 0; it < 4; ++it) {
      int p = ((it * 4 + wv) << 10) | (ln << 4);
      int row = p >> 7, colb = p & 127;
      const char* ga = (const char*)A + ((size_t)(m0 + row) * K + k0) * 2 + (colb ^ ((row & 7) << 4));
      const char* gb = (const char*)B + ((size_t)(n0 + row) * K + k0) * 2 + (colb ^ ((row & 7) << 4));
      __builtin_amdgcn_global_load_lds(GAS(ga), LAS(sA + ((it * 4 + wv) << 10)), 16, 0, 0);
      __builtin_amdgcn_global_load_lds(GAS(gb), LAS(sB + ((it * 4 + wv) << 10)), 16, 0, 0);
    }
    __syncthreads();
#pragma unroll
    for (int kk = 0; kk < 2; ++kk) {
      bf16x8 af[4], bfr[4];
#pragma unroll
      for (int i = 0; i < 4; ++i) {
        int row = wm * 64 + i * 16 + lr;
        af[i] = *(const bf16x8*)(sA + row * 128 + ((kk * 64 + lg * 16) ^ ((row & 7) << 4)));
      }
#pragma unroll
      for (int j = 0; j < 4; ++j) {
        int row = wn * 64 + j * 16 + lr;
        bfr[j] = *(const bf16x8*)(sB + row * 128 + ((kk * 64 + lg * 16) ^ ((row & 7) << 4)));
      }
#pragma unroll
      for (int i = 0; i < 4; ++i)
#pragma unroll
        for (int j = 0; j < 4; ++j)
          acc[i][j] = __builtin_amdgcn_mfma_f32_16x16x32_bf16(af[i], bfr[j], acc[i][j], 0, 0, 0);
    }
    __syncthreads();
  }
#pragma unroll
  for (int i = 0; i < 4; ++i) {
    int m = m0 + wm * 64 + i * 16 + lg * 4;
#pragma unroll
    for (int j = 0; j < 4; ++j) {
      int n = n0 + wn * 64 + j * 16 + lr;
      if (OUTMODE == 3) {
        if (n0 < 1024) {
#pragma unroll
          for (int r = 0; r < 4; ++r)
            ((unsigned short*)C)[(size_t)(m + r) * 1024 + n] = f2bf(acc[i][j][r]);
        } else if (n0 < 2048) {
#pragma unroll
          for (int r = 0; r < 4; ++r)
            ((unsigned short*)C2)[(size_t)(m + r) * 1024 + (n - 1024)] = f2bf(acc[i][j][r]);
        } else {
          u16x4 o;
#pragma unroll
          for (int r = 0; r < 4; ++r) o[r] = f2bf(acc[i][j][r]);
          *(u16x4*)((unsigned short*)C3 + (size_t)(n - 2048) * 4096 + m) = o;
        }
      } else if (OUTMODE == 2) {
        u16x4 o;
#pragma unroll
        for (int r = 0; r < 4; ++r) o[r] = f2bf(acc[i][j][r]);
        *(u16x4*)((unsigned short*)C + (size_t)n * ldc + m) = o;
      } else {
        float bv = bias ? bias[n] : 0.f;
#pragma unroll
        for (int r = 0; r < 4; ++r) {
          float v = acc[i][j][r] + bv;
          if (RELU) v = fmaxf(v, 0.f);
          if (OUTMODE == 1) ((unsigned short*)C)[(size_t)(m + r) * ldc + n] = f2bf(v);
          else ((float*)C)[(size_t)(m + r) * ldc + n] = v;
        }
      }
    }
  }
}

// ---------------- fused flash attention, split-KV, 32 q-rows/wave, KV tiles 32 -------
// grid (N/64, H, 2): block = 2 waves x 32 q rows, one KV-half (2048 = 64 tiles of 32).
// K and V both double-buffered (8KB tiles). Each kf/vf LDS read feeds 2 MFMAs.
// Register-lean: S[2][2] (16), bias same-iter (32), no reg staging -> ~200 VGPR, no spill.
// 4 blocks/CU = 8 waves/CU. Fixed-shift softmax (C=16); partial O + lsum, k_comb joins.
__global__ __launch_bounds__(128, 2)
void k_attn(const unsigned short* __restrict__ Qb, const unsigned short* __restrict__ Kb,
            const unsigned short* __restrict__ Vtb, const float* __restrict__ Wm,
            const float* __restrict__ Cm, const float* __restrict__ bwv,
            const float* __restrict__ bcv, unsigned short* __restrict__ Opart,
            float* __restrict__ Ls)
{
  __shared__ char sK[2 * 8192];            // [buf][32 kv][128 d] bf16, xor-swizzled
  __shared__ char sV[2 * 8192];            // [buf][128 d][32 kv] bf16, xor-swizzled (64B rows)
  __shared__ unsigned short sP[2][32][40]; // pitch 40 shorts (80B, 16B-aligned rows)
  const int t = threadIdx.x, wv = t >> 6, ln = t & 63;
  const int lr = ln & 15, lg = ln >> 4;
  const int h = blockIdx.y, z = blockIdx.z;
  const int q0 = blockIdx.x * 64 + wv * 32;
  const int kvb = z * 2048;
  const float L2E = 1.4426950408889634f;
  const float scaleL = 0.08838834764831845f * L2E; // (1/sqrt(128)) * log2e
  const float bw2 = bwv[h] * L2E, bc2 = bcv[h] * L2E;
  const float CL = 16.0f * L2E;

  // Q fragments: [a-frag][k-chunk], in registers for the whole kernel (32 VGPRs)
  bf16x8 qf[2][4];
#pragma unroll
  for (int a = 0; a < 2; ++a)
#pragma unroll
    for (int kk = 0; kk < 4; ++kk)
      qf[a][kk] = *(const bf16x8*)(Qb + (size_t)(q0 + a * 16 + lr) * 1024 + h * 128 + kk * 32 + lg * 8);

  f32x4 Oacc[2][8] = {};
  float lsum[2][4] = {};

  auto stageKV = [&](int buf, int kv) {
#pragma unroll
    for (int i4 = 0; i4 < 4; ++i4) {
      int p = ((i4 * 2 + wv) << 10) | (ln << 4);
      {
        int row = p >> 8, colb = p & 255;   // K: [32 kv][256B]
        const char* g = (const char*)Kb + ((size_t)(kv + row) * 1024 + h * 128) * 2 + (colb ^ ((row & 7) << 4));
        __builtin_amdgcn_global_load_lds(GAS(g), LAS(sK + buf * 8192 + p), 16, 0, 0);
      }
      {
        int row = p >> 6, colb = p & 63;    // V^T: [128 d][64B]
        const char* g = (const char*)Vtb + ((size_t)(h * 128 + row) * 4096 + kv) * 2 + (colb ^ ((row & 3) << 4));
        __builtin_amdgcn_global_load_lds(GAS(g), LAS(sV + buf * 8192 + p), 16, 0, 0);
      }
    }
  };

  // prologue: stage tile 0 of this half
  stageKV(0, kvb);
  __syncthreads();

#pragma unroll 2
  for (int it = 0; it < 64; ++it) {
    const int cur = it & 1;
    const int kv0 = kvb + (it << 5);
    const char* sKc = sK + cur * 8192;
    const char* sVc = sV + cur * 8192;

    // bias loads for THIS tile, issued FIRST (older than staging -> partial vmcnt wait)
    float wmn[2][2][4], cmn[2][2][4];
#pragma unroll
    for (int a = 0; a < 2; ++a)
#pragma unroll
      for (int r = 0; r < 4; ++r) {
        size_t off = (size_t)(q0 + a * 16 + lg * 4 + r) * 4096 + kv0 + lr;
#pragma unroll
        for (int j = 0; j < 2; ++j) {
          wmn[a][j][r] = Wm[off + j * 16];
          cmn[a][j][r] = Cm[off + j * 16];
        }
      }

    // prefetch next K/V tile into the other buffers
    if (it < 63) stageKV(cur ^ 1, kv0 + 32);

    // S = Q K^T  (4 d-ksteps x 2 kv-ntiles x 2 a-frags)
    f32x4 S[2][2] = {};
    __builtin_amdgcn_s_setprio(1);
#pragma unroll
    for (int kk = 0; kk < 4; ++kk)
#pragma unroll
      for (int j = 0; j < 2; ++j) {
        int row = j * 16 + lr;
        bf16x8 kf = *(const bf16x8*)(sKc + row * 256 + ((kk * 64 + lg * 16) ^ ((row & 7) << 4)));
        S[0][j] = __builtin_amdgcn_mfma_f32_16x16x32_bf16(qf[0][kk], kf, S[0][j], 0, 0, 0);
        S[1][j] = __builtin_amdgcn_mfma_f32_16x16x32_bf16(qf[1][kk], kf, S[1][j], 0, 0, 0);
      }
    __builtin_amdgcn_s_setprio(0);

    // softmax numerators: p = exp2(S*scaleL + bias - C); per-lane denominator
#pragma unroll
    for (int a = 0; a < 2; ++a)
#pragma unroll
      for (int j = 0; j < 2; ++j)
#pragma unroll
        for (int r = 0; r < 4; ++r) {
          float fb = fmaf(wmn[a][j][r], bw2, fmaf(cmn[a][j][r], bc2, -CL));
          float p = fexp2(fmaf(S[a][j][r], scaleL, fb));
          lsum[a][r] += p;
          sP[wv][a * 16 + lg * 4 + r][j * 16 + lr] = f2bf(p);
        }

    // O += P V   (8 d-ntiles x 2 a-frags, single 32-k step)
    __builtin_amdgcn_s_setprio(1);
    {
      bf16x8 pf0 = *(const bf16x8*)((const char*)sP[wv] + (size_t)lr * 80 + lg * 16);
      bf16x8 pf1 = *(const bf16x8*)((const char*)sP[wv] + (size_t)(16 + lr) * 80 + lg * 16);
#pragma unroll
      for (int n = 0; n < 8; ++n) {
        int row = n * 16 + lr;
        bf16x8 vf = *(const bf16x8*)(sVc + row * 64 + ((lg * 16) ^ ((row & 3) << 4)));
        Oacc[0][n] = __builtin_amdgcn_mfma_f32_16x16x32_bf16(pf0, vf, Oacc[0][n], 0, 0, 0);
        Oacc[1][n] = __builtin_amdgcn_mfma_f32_16x16x32_bf16(pf1, vf, Oacc[1][n], 0, 0, 0);
      }
    }
    __builtin_amdgcn_s_setprio(0);

    __syncthreads();  // staging(t+1) drained (full-iter cover); cur-buffer reads done
  }

  // partial denominator reduce across the 16 lanes of each row group
#pragma unroll
  for (int a = 0; a < 2; ++a)
#pragma unroll
    for (int r = 0; r < 4; ++r) {
#pragma unroll
      for (int msk = 1; msk < 16; msk <<= 1) lsum[a][r] += __shfl_xor(lsum[a][r], msk, 64);
    }

  // store unnormalized bf16 partial O + f32 partial lsum
  unsigned short* Op = Opart + (size_t)z * 4194304;
#pragma unroll
  for (int a = 0; a < 2; ++a)
#pragma unroll
    for (int n = 0; n < 8; ++n)
#pragma unroll
      for (int r = 0; r < 4; ++r) {
        int qg = q0 + a * 16 + lg * 4 + r;
        Op[(size_t)qg * 1024 + h * 128 + n * 16 + lr] = f2bf(Oacc[a][n][r]);
      }
  if (lr == 0) {
#pragma unroll
    for (int a = 0; a < 2; ++a)
#pragma unroll
      for (int r = 0; r < 4; ++r)
        Ls[(size_t)(z * 8 + h) * 4096 + q0 + a * 16 + lg * 4 + r] = lsum[a][r];
  }
}

// ---------------- combine split-KV partials: O = (O0+O1)/(l0+l1) (in-place safe) -----
__global__ __launch_bounds__(256)
void k_comb(const unsigned short* __restrict__ P, const float* __restrict__ Ls,
            unsigned short* __restrict__ out)
{
  const int q = blockIdx.x, t = threadIdx.x;
  const int h = t >> 5;
  float l = Ls[(size_t)h * 4096 + q] + Ls[(size_t)(8 + h) * 4096 + q];
  float inv = 1.0f / l;
  size_t o = (size_t)q * 1024 + t * 4;
  u16x4 a = *(const u16x4*)(P + o);
  u16x4 b = *(const u16x4*)(P + 4194304 + o);
  u16x4 c;
#pragma unroll
  for (int e = 0; e < 4; ++e) c[e] = f2bf((bf2f(a[e]) + bf2f(b[e])) * inv);
  *(u16x4*)(out + o) = c;
}

// ---------------- fused residual + LayerNorm (f32 out + optional bf16 out) -----------
__global__ __launch_bounds__(256, 4)
void k_ln(const float* __restrict__ resid, const float* __restrict__ delta,
          const float* __restrict__ g, const float* __restrict__ b,
          float* __restrict__ outf, unsigned short* __restrict__ outb)
{
  const int row = blockIdx.x, t = threadIdx.x;
  const float* pr = resid + (size_t)row * 1024;
  const float* pd = delta + (size_t)row * 1024;
  f32x4 a = *(const f32x4*)(pr + t * 4);
  f32x4 d = *(const f32x4*)(pd + t * 4);
  f32x4 x;
#pragma unroll
  for (int e = 0; e < 4; ++e) x[e] = a[e] + d[e];
  float s = x[0] + x[1] + x[2] + x[3];
  float ss = x[0]*x[0] + x[1]*x[1] + x[2]*x[2] + x[3]*x[3];
#pragma unroll
  for (int msk = 1; msk < 64; msk <<= 1) {
    s += __shfl_xor(s, msk, 64);
    ss += __shfl_xor(ss, msk, 64);
  }
  __shared__ float red[8];
  if ((t & 63) == 0) { red[(t >> 6) * 2] = s; red[(t >> 6) * 2 + 1] = ss; }
  __syncthreads();
  s = red[0] + red[2] + red[4] + red[6];
  ss = red[1] + red[3] + red[5] + red[7];
  float mu = s * (1.f / 1024.f);
  float var = ss * (1.f / 1024.f) - mu * mu;
  float rstd = rsqrtf(var + 1e-5f);
#pragma unroll
  for (int e = 0; e < 4; ++e) {
    int c = t * 4 + e;
    float y = (x[e] - mu) * rstd * g[c] + b[c];
    outf[(size_t)row * 1024 + c] = y;
    if (outb) outb[(size_t)row * 1024 + c] = f2bf(y);
  }
}

// ---------------- launch ----------------
extern "C" void kernel_launch(void* const* d_in, const int* in_sizes, int n_in,
                              void* d_out, int out_size, void* d_ws, size_t ws_size,
                              hipStream_t stream) {
  const float* x   = (const float*)d_in[0];
  const float* Wm  = (const float*)d_in[1];
  const float* Cm  = (const float*)d_in[2];
  const float* Wq  = (const float*)d_in[3];
  const float* Wk  = (const float*)d_in[4];
  const float* Wv  = (const float*)d_in[5];
  const float* Wo  = (const float*)d_in[6];
  const float* bo  = (const float*)d_in[7];
  const float* bw  = (const float*)d_in[8];
  const float* bc  = (const float*)d_in[9];
  const float* g1  = (const float*)d_in[10];
  const float* be1 = (const float*)d_in[11];
  const float* g2  = (const float*)d_in[12];
  const float* be2 = (const float*)d_in[13];
  const float* W1  = (const float*)d_in[14];
  const float* b1  = (const float*)d_in[15];
  const float* W2  = (const float*)d_in[16];
  const float* b2  = (const float*)d_in[17];

  char* ws = (char*)d_ws;
  const size_t MB = 1u << 20;
  unsigned short* xb   = (unsigned short*)(ws);            // 8MB  (later reused as x1b)
  unsigned short* Wqkv = (unsigned short*)(ws + 8  * MB);  // 6MB stacked [3072][1024]
  unsigned short* Wob  = (unsigned short*)(ws + 14 * MB);  // 2MB
  unsigned short* W1b  = (unsigned short*)(ws + 16 * MB);  // 4MB
  unsigned short* W2b  = (unsigned short*)(ws + 20 * MB);  // 4MB
  unsigned short* Qb   = (unsigned short*)(ws + 24 * MB);  // 8MB
  unsigned short* Kb   = (unsigned short*)(ws + 32 * MB);  // 8MB
  unsigned short* Vtb  = (unsigned short*)(ws + 40 * MB);  // 8MB, V TRANSPOSED [1024][4096]
  unsigned short* Obuf = (unsigned short*)(ws + 48 * MB);  // 16MB as Opart[2][4096][1024];
                                                           // combined in-place into first 8MB
  float*          Lsb  = (float*)(ws + 64 * MB);           // 256KB lsum partials
  float*          tmp  = (float*)(ws + 56 * MB);           // 16MB (Wo out, then FF2 out)
                                                           //   clobbers Opart[1]+Ls (dead)
  float*          x1f  = (float*)(ws + 24 * MB);           // 16MB (over Qb/Kb, dead by then)
  unsigned short* x1b  = (unsigned short*)(ws);            // over xb (dead)
  unsigned short* hb   = (unsigned short*)(ws + 40 * MB);  // 16MB (over Vtb/Obuf, dead)

  // 1. all bf16 conversions in ONE launch (Wq/Wk/Wv stacked into Wqkv)
  CvtArgs ca;
  ca.x = x; ca.wq = Wq; ca.wk = Wk; ca.wv = Wv; ca.wo = Wo; ca.w1 = W1; ca.w2 = W2;
  ca.xb = xb; ca.wqd = Wqkv; ca.wkd = Wqkv + 1024 * 1024; ca.wvd = Wqkv + 2048 * 1024;
  ca.wod = Wob; ca.w1d = W1b; ca.w2d = W2b;
  k_convall<<<12288, 256, 0, stream>>>(ca);

  // 2. fused QKV projection: cols 0-1023 -> Qb, 1024-2047 -> Kb, 2048-3071 -> Vt^T
  k_gemm_bt<0,3><<<dim3(24, 32), 256, 0, stream>>>(xb, Wqkv, nullptr, Qb,
                                                   4096, 3072, 1024, 1024, Kb, Vtb);

  // 3. fused attention, split-KV (z = 2 halves), then combine
  k_attn<<<dim3(64, 8, 2), 128, 0, stream>>>(Qb, Kb, Vtb, Wm, Cm, bw, bc, Obuf, Lsb);
  k_comb<<<4096, 256, 0, stream>>>(Obuf, Lsb, Obuf);

  // 4. output projection (f32 out + bias)
  k_gemm_bt<0,0><<<dim3(8, 32), 256, 0, stream>>>(Obuf, Wob, bo, tmp, 4096, 1024, 1024, 1024);

  // 5. LN1: x1 = LN(x + attn_out)
  k_ln<<<4096, 256, 0, stream>>>(x, tmp, g1, be1, x1f, x1b);

  // 6. FF1 with ReLU (bf16 out)
  k_gemm_bt<1,1><<<dim3(16, 32), 256, 0, stream>>>(x1b, W1b, b1, hb, 4096, 2048, 1024, 2048);

  // 7. FF2 (f32 out)
  k_gemm_bt<0,0><<<dim3(8, 32), 256, 0, stream>>>(hb, W2b, b2, tmp, 4096, 1024, 2048, 1024);

  // 8. LN2 -> d_out
  k_ln<<<4096, 256, 0, stream>>>(x1f, tmp, g2, be2, (float*)d_out, nullptr);
}

// Round 9
// 307.080 us; speedup vs baseline: 1.3471x; 1.0807x over previous
//
#include <hip/hip_runtime.h>

typedef __attribute__((ext_vector_type(8))) short bf16x8;
typedef __attribute__((ext_vector_type(4))) float f32x4;
typedef __attribute__((ext_vector_type(4))) unsigned short u16x4;

#define GAS(p) ((const __attribute__((address_space(1))) void*)(p))
#define LAS(p) ((__attribute__((address_space(3))) void*)(p))

__device__ __forceinline__ unsigned short f2bf(float f) {
  unsigned int u = __float_as_uint(f);
  u += 0x7fffu + ((u >> 16) & 1u);
  return (unsigned short)(u >> 16);
}

__device__ __forceinline__ float bf2f(unsigned short u) {
  return __uint_as_float(((unsigned int)u) << 16);
}

__device__ __forceinline__ float fexp2(float x) {
  float r;
  asm("v_exp_f32 %0, %1" : "=v"(r) : "v"(x));
  return r;
}

// ---------------- fused f32 -> bf16 convert (all 7 tensors, 1 launch) ----------------
struct CvtArgs {
  const float *x, *wq, *wk, *wv, *wo, *w1, *w2;
  unsigned short *xb, *wqd, *wkd, *wvd, *wod, *w1d, *w2d;
};
__global__ __launch_bounds__(256) void k_convall(CvtArgs a) {
  long i = (long)blockIdx.x * 256 + threadIdx.x;  // vec4 index
  const float* s;
  unsigned short* d;
  long j;
  if (i < 1048576)      { s = a.x;  d = a.xb;  j = i; }
  else if (i < 1310720) { s = a.wq; d = a.wqd; j = i - 1048576; }
  else if (i < 1572864) { s = a.wk; d = a.wkd; j = i - 1310720; }
  else if (i < 1835008) { s = a.wv; d = a.wvd; j = i - 1572864; }
  else if (i < 2097152) { s = a.wo; d = a.wod; j = i - 1835008; }
  else if (i < 2621440) { s = a.w1; d = a.w1d; j = i - 2097152; }
  else                  { s = a.w2; d = a.w2d; j = i - 2621440; }
  f32x4 v = *(const f32x4*)(s + j * 4);
  u16x4 o;
  o[0] = f2bf(v[0]); o[1] = f2bf(v[1]); o[2] = f2bf(v[2]); o[3] = f2bf(v[3]);
  *(u16x4*)(d + j * 4) = o;
}

// ---------------- bf16 GEMM: C[M,N] = A[M,K] * B[N,K]^T ------------------------------
// Tile BM x 128, BK=64, 4 waves in 2x2 (wave tile BM/2 x 64).
// OUTMODE: 0 = f32 (+bias, relu opt), 1 = bf16, 2 = bf16 TRANSPOSED (C_t[n][m], ldc=M),
//          3 = QKV router: cols [0,1024)->C, [1024,2048)->C2, [2048,3072)->C3 transposed.
template<int RELU, int OUTMODE, int BM>
__global__ __launch_bounds__(256, (BM == 64 ? 4 : 2))
void k_gemm_bt(const unsigned short* __restrict__ A, const unsigned short* __restrict__ B,
               const float* __restrict__ bias, void* __restrict__ C,
               int M, int N, int K, int ldc,
               void* __restrict__ C2 = nullptr, void* __restrict__ C3 = nullptr)
{
  __shared__ char sA[BM * 128];
  __shared__ char sB[128 * 128];
  const int t = threadIdx.x, wv = t >> 6, ln = t & 63;
  const int lr = ln & 15, lg = ln >> 4;
  const int m0 = blockIdx.y * BM, n0 = blockIdx.x * 128;
  const int wm = wv >> 1, wn = wv & 1;
  constexpr int MF = BM / 32;   // m-fragments per wave
  f32x4 acc[MF][4] = {};
  for (int k0 = 0; k0 < K; k0 += 64) {
#pragma unroll
    for (int c2 = 0; c2 < BM / 32; ++c2) {      // A chunks: BM*128/1024
      int p = ((c2 * 4 + wv) << 10) | (ln << 4);
      int row = p >> 7, colb = p & 127;
      const char* ga = (const char*)A + ((size_t)(m0 + row) * K + k0) * 2 + (colb ^ ((row & 7) << 4));
      __builtin_amdgcn_global_load_lds(GAS(ga), LAS(sA + ((c2 * 4 + wv) << 10)), 16, 0, 0);
    }
#pragma unroll
    for (int c2 = 0; c2 < 4; ++c2) {            // B chunks: 16
      int p = ((c2 * 4 + wv) << 10) | (ln << 4);
      int row = p >> 7, colb = p & 127;
      const char* gb = (const char*)B + ((size_t)(n0 + row) * K + k0) * 2 + (colb ^ ((row & 7) << 4));
      __builtin_amdgcn_global_load_lds(GAS(gb), LAS(sB + ((c2 * 4 + wv) << 10)), 16, 0, 0);
    }
    __syncthreads();
#pragma unroll
    for (int kk = 0; kk < 2; ++kk) {
      bf16x8 af[MF], bfr[4];
#pragma unroll
      for (int i = 0; i < MF; ++i) {
        int row = wm * (BM / 2) + i * 16 + lr;
        af[i] = *(const bf16x8*)(sA + row * 128 + ((kk * 64 + lg * 16) ^ ((row & 7) << 4)));
      }
#pragma unroll
      for (int j = 0; j < 4; ++j) {
        int row = wn * 64 + j * 16 + lr;
        bfr[j] = *(const bf16x8*)(sB + row * 128 + ((kk * 64 + lg * 16) ^ ((row & 7) << 4)));
      }
#pragma unroll
      for (int i = 0; i < MF; ++i)
#pragma unroll
        for (int j = 0; j < 4; ++j)
          acc[i][j] = __builtin_amdgcn_mfma_f32_16x16x32_bf16(af[i], bfr[j], acc[i][j], 0, 0, 0);
    }
    __syncthreads();
  }
#pragma unroll
  for (int i = 0; i < MF; ++i) {
    int m = m0 + wm * (BM / 2) + i * 16 + lg * 4;
#pragma unroll
    for (int j = 0; j < 4; ++j) {
      int n = n0 + wn * 64 + j * 16 + lr;
      if (OUTMODE == 3) {
        if (n0 < 1024) {
#pragma unroll
          for (int r = 0; r < 4; ++r)
            ((unsigned short*)C)[(size_t)(m + r) * 1024 + n] = f2bf(acc[i][j][r]);
        } else if (n0 < 2048) {
#pragma unroll
          for (int r = 0; r < 4; ++r)
            ((unsigned short*)C2)[(size_t)(m + r) * 1024 + (n - 1024)] = f2bf(acc[i][j][r]);
        } else {
          u16x4 o;
#pragma unroll
          for (int r = 0; r < 4; ++r) o[r] = f2bf(acc[i][j][r]);
          *(u16x4*)((unsigned short*)C3 + (size_t)(n - 2048) * 4096 + m) = o;
        }
      } else if (OUTMODE == 2) {
        u16x4 o;
#pragma unroll
        for (int r = 0; r < 4; ++r) o[r] = f2bf(acc[i][j][r]);
        *(u16x4*)((unsigned short*)C + (size_t)n * ldc + m) = o;
      } else {
        float bv = bias ? bias[n] : 0.f;
#pragma unroll
        for (int r = 0; r < 4; ++r) {
          float v = acc[i][j][r] + bv;
          if (RELU) v = fmaxf(v, 0.f);
          if (OUTMODE == 1) ((unsigned short*)C)[(size_t)(m + r) * ldc + n] = f2bf(v);
          else ((float*)C)[(size_t)(m + r) * ldc + n] = v;
        }
      }
    }
  }
}

// ---------------- fused flash attention, split-KV, 16 waves/CU ----------------------
// grid (N/64, H, 2): block = 4 waves x 16 q rows, one KV-half (2048 = 64 tiles of 32).
// K and V double-buffered 8KB tiles; LDS 37.5KB -> 4 blocks/CU x 4 waves = 16 waves/CU
// (4 waves/SIMD — the TLP experiment). R3's proven per-wave structure otherwise.
// Fixed-shift softmax (C=16); partial O + lsum per half, k_comb joins.
__global__ __launch_bounds__(256, 4)
void k_attn(const unsigned short* __restrict__ Qb, const unsigned short* __restrict__ Kb,
            const unsigned short* __restrict__ Vtb, const float* __restrict__ Wm,
            const float* __restrict__ Cm, const float* __restrict__ bwv,
            const float* __restrict__ bcv, unsigned short* __restrict__ Opart,
            float* __restrict__ Ls)
{
  __shared__ char sK[2 * 8192];            // [buf][32 kv][256B d] bf16, xor-swizzled
  __shared__ char sV[2 * 8192];            // [buf][128 d][64B kv] bf16, xor-swizzled
  __shared__ unsigned short sP[4][16][44]; // pitch 44 -> disjoint bank octets per write
  const int t = threadIdx.x, wv = t >> 6, ln = t & 63;
  const int lr = ln & 15, lg = ln >> 4;
  const int h = blockIdx.y, z = blockIdx.z;
  const int q0 = blockIdx.x * 64 + wv * 16;
  const int kvb = z * 2048;
  const float L2E = 1.4426950408889634f;
  const float scaleL = 0.08838834764831845f * L2E; // (1/sqrt(128)) * log2e
  const float bw2 = bwv[h] * L2E, bc2 = bcv[h] * L2E;
  const float CL = 16.0f * L2E;

  // Q fragments (registers for whole kernel)
  bf16x8 qf[4];
#pragma unroll
  for (int kk = 0; kk < 4; ++kk)
    qf[kk] = *(const bf16x8*)(Qb + (size_t)(q0 + lr) * 1024 + h * 128 + kk * 32 + lg * 8);

  // per-row graph-bias pointers
  const float* wr[4];
  const float* cr[4];
#pragma unroll
  for (int r = 0; r < 4; ++r) {
    size_t off = (size_t)(q0 + lg * 4 + r) * 4096 + lr;
    wr[r] = Wm + off;
    cr[r] = Cm + off;
  }

  f32x4 Oacc[8] = {};
  float lsum[4] = {0.f, 0.f, 0.f, 0.f};

  auto stageKV = [&](int buf, int kv) {
#pragma unroll
    for (int c2 = 0; c2 < 2; ++c2) {
      int p = ((c2 * 4 + wv) << 10) | (ln << 4);
      {
        int row = p >> 8, colb = p & 255;   // K: 32 rows x 256B
        const char* g = (const char*)Kb + ((size_t)(kv + row) * 1024 + h * 128) * 2 + (colb ^ ((row & 7) << 4));
        __builtin_amdgcn_global_load_lds(GAS(g), LAS(sK + buf * 8192 + p), 16, 0, 0);
      }
      {
        int row = p >> 6, colb = p & 63;    // V^T: 128 rows x 64B
        const char* g = (const char*)Vtb + ((size_t)(h * 128 + row) * 4096 + kv) * 2 + (colb ^ ((row & 3) << 4));
        __builtin_amdgcn_global_load_lds(GAS(g), LAS(sV + buf * 8192 + p), 16, 0, 0);
      }
    }
  };

  // prologue
  stageKV(0, kvb);
  __syncthreads();

  for (int it = 0; it < 64; ++it) {
    const int cur = it & 1;
    const int kv0 = kvb + (it << 5);
    const char* sKc = sK + cur * 8192;
    const char* sVc = sV + cur * 8192;

    // bias loads for THIS tile, issued first (latency hides under QK^T MFMA)
    float wmn[2][4], cmn[2][4];
#pragma unroll
    for (int j = 0; j < 2; ++j)
#pragma unroll
      for (int r = 0; r < 4; ++r) {
        wmn[j][r] = wr[r][kv0 + j * 16];
        cmn[j][r] = cr[r][kv0 + j * 16];
      }

    // prefetch next K/V tile into the other buffers
    if (it < 63) stageKV(cur ^ 1, kv0 + 32);

    // S = Q K^T  (4 d-ksteps x 2 kv-ntiles)
    f32x4 S[2] = {};
    __builtin_amdgcn_s_setprio(1);
#pragma unroll
    for (int kk = 0; kk < 4; ++kk)
#pragma unroll
      for (int j = 0; j < 2; ++j) {
        int row = j * 16 + lr;
        bf16x8 kf = *(const bf16x8*)(sKc + row * 256 + ((kk * 64 + lg * 16) ^ ((row & 7) << 4)));
        S[j] = __builtin_amdgcn_mfma_f32_16x16x32_bf16(qf[kk], kf, S[j], 0, 0, 0);
      }
    __builtin_amdgcn_s_setprio(0);

    // softmax numerators: p = exp2(S*scaleL + bias - C); per-lane denominator
#pragma unroll
    for (int j = 0; j < 2; ++j)
#pragma unroll
      for (int r = 0; r < 4; ++r) {
        float fb = fmaf(wmn[j][r], bw2, fmaf(cmn[j][r], bc2, -CL));
        float p = fexp2(fmaf(S[j][r], scaleL, fb));
        lsum[r] += p;
        sP[wv][lg * 4 + r][j * 16 + lr] = f2bf(p);
      }

    // O += P V   (8 d-ntiles, single 32-k step)
    __builtin_amdgcn_s_setprio(1);
    {
      bf16x8 pf = *(const bf16x8*)((const char*)sP[wv] + (size_t)lr * 88 + lg * 16);
#pragma unroll
      for (int n = 0; n < 8; ++n) {
        int row = n * 16 + lr;
        bf16x8 vf = *(const bf16x8*)(sVc + row * 64 + ((lg * 16) ^ ((row & 3) << 4)));
        Oacc[n] = __builtin_amdgcn_mfma_f32_16x16x32_bf16(pf, vf, Oacc[n], 0, 0, 0);
      }
    }
    __builtin_amdgcn_s_setprio(0);

    __syncthreads();  // staging(t+1) drained (full-iter cover); cur-buffer reads done
  }

  // partial denominator reduce across the 16 lanes of each row group
#pragma unroll
  for (int r = 0; r < 4; ++r) {
#pragma unroll
    for (int msk = 1; msk < 16; msk <<= 1) lsum[r] += __shfl_xor(lsum[r], msk, 64);
  }

  // store unnormalized bf16 partial O + f32 partial lsum
  unsigned short* Op = Opart + (size_t)z * 4194304;
#pragma unroll
  for (int n = 0; n < 8; ++n)
#pragma unroll
    for (int r = 0; r < 4; ++r) {
      int qg = q0 + lg * 4 + r;
      Op[(size_t)qg * 1024 + h * 128 + n * 16 + lr] = f2bf(Oacc[n][r]);
    }
  if (lr == 0) {
#pragma unroll
    for (int r = 0; r < 4; ++r)
      Ls[(size_t)(z * 8 + h) * 4096 + q0 + lg * 4 + r] = lsum[r];
  }
}

// ---------------- combine split-KV partials: O = (O0+O1)/(l0+l1) (in-place safe) -----
__global__ __launch_bounds__(256)
void k_comb(const unsigned short* __restrict__ P, const float* __restrict__ Ls,
            unsigned short* __restrict__ out)
{
  const int q = blockIdx.x, t = threadIdx.x;
  const int h = t >> 5;
  float l = Ls[(size_t)h * 4096 + q] + Ls[(size_t)(8 + h) * 4096 + q];
  float inv = 1.0f / l;
  size_t o = (size_t)q * 1024 + t * 4;
  u16x4 a = *(const u16x4*)(P + o);
  u16x4 b = *(const u16x4*)(P + 4194304 + o);
  u16x4 c;
#pragma unroll
  for (int e = 0; e < 4; ++e) c[e] = f2bf((bf2f(a[e]) + bf2f(b[e])) * inv);
  *(u16x4*)(out + o) = c;
}

// ---------------- fused residual + LayerNorm (f32 out + optional bf16 out) -----------
__global__ __launch_bounds__(256, 4)
void k_ln(const float* __restrict__ resid, const float* __restrict__ delta,
          const float* __restrict__ g, const float* __restrict__ b,
          float* __restrict__ outf, unsigned short* __restrict__ outb)
{
  const int row = blockIdx.x, t = threadIdx.x;
  const float* pr = resid + (size_t)row * 1024;
  const float* pd = delta + (size_t)row * 1024;
  f32x4 a = *(const f32x4*)(pr + t * 4);
  f32x4 d = *(const f32x4*)(pd + t * 4);
  f32x4 x;
#pragma unroll
  for (int e = 0; e < 4; ++e) x[e] = a[e] + d[e];
  float s = x[0] + x[1] + x[2] + x[3];
  float ss = x[0]*x[0] + x[1]*x[1] + x[2]*x[2] + x[3]*x[3];
#pragma unroll
  for (int msk = 1; msk < 64; msk <<= 1) {
    s += __shfl_xor(s, msk, 64);
    ss += __shfl_xor(ss, msk, 64);
  }
  __shared__ float red[8];
  if ((t & 63) == 0) { red[(t >> 6) * 2] = s; red[(t >> 6) * 2 + 1] = ss; }
  __syncthreads();
  s = red[0] + red[2] + red[4] + red[6];
  ss = red[1] + red[3] + red[5] + red[7];
  float mu = s * (1.f / 1024.f);
  float var = ss * (1.f / 1024.f) - mu * mu;
  float rstd = rsqrtf(var + 1e-5f);
#pragma unroll
  for (int e = 0; e < 4; ++e) {
    int c = t * 4 + e;
    float y = (x[e] - mu) * rstd * g[c] + b[c];
    outf[(size_t)row * 1024 + c] = y;
    if (outb) outb[(size_t)row * 1024 + c] = f2bf(y);
  }
}

// ---------------- launch ----------------
extern "C" void kernel_launch(void* const* d_in, const int* in_sizes, int n_in,
                              void* d_out, int out_size, void* d_ws, size_t ws_size,
                              hipStream_t stream) {
  const float* x   = (const float*)d_in[0];
  const float* Wm  = (const float*)d_in[1];
  const float* Cm  = (const float*)d_in[2];
  const float* Wq  = (const float*)d_in[3];
  const float* Wk  = (const float*)d_in[4];
  const float* Wv  = (const float*)d_in[5];
  const float* Wo  = (const float*)d_in[6];
  const float* bo  = (const float*)d_in[7];
  const float* bw  = (const float*)d_in[8];
  const float* bc  = (const float*)d_in[9];
  const float* g1  = (const float*)d_in[10];
  const float* be1 = (const float*)d_in[11];
  const float* g2  = (const float*)d_in[12];
  const float* be2 = (const float*)d_in[13];
  const float* W1  = (const float*)d_in[14];
  const float* b1  = (const float*)d_in[15];
  const float* W2  = (const float*)d_in[16];
  const float* b2  = (const float*)d_in[17];

  char* ws = (char*)d_ws;
  const size_t MB = 1u << 20;
  unsigned short* xb   = (unsigned short*)(ws);            // 8MB  (later reused as x1b)
  unsigned short* Wqkv = (unsigned short*)(ws + 8  * MB);  // 6MB stacked [3072][1024]
  unsigned short* Wob  = (unsigned short*)(ws + 14 * MB);  // 2MB
  unsigned short* W1b  = (unsigned short*)(ws + 16 * MB);  // 4MB
  unsigned short* W2b  = (unsigned short*)(ws + 20 * MB);  // 4MB
  unsigned short* Qb   = (unsigned short*)(ws + 24 * MB);  // 8MB
  unsigned short* Kb   = (unsigned short*)(ws + 32 * MB);  // 8MB
  unsigned short* Vtb  = (unsigned short*)(ws + 40 * MB);  // 8MB, V TRANSPOSED [1024][4096]
  unsigned short* Obuf = (unsigned short*)(ws + 48 * MB);  // 16MB as Opart[2][4096][1024];
                                                           // combined in-place into first 8MB
  float*          Lsb  = (float*)(ws + 64 * MB);           // 256KB lsum partials
  float*          tmp  = (float*)(ws + 56 * MB);           // 16MB (Wo out, then FF2 out)
                                                           //   clobbers Opart[1]+Ls (dead)
  float*          x1f  = (float*)(ws + 24 * MB);           // 16MB (over Qb/Kb, dead by then)
  unsigned short* x1b  = (unsigned short*)(ws);            // over xb (dead)
  unsigned short* hb   = (unsigned short*)(ws + 40 * MB);  // 16MB (over Vtb/Obuf, dead)

  // 1. all bf16 conversions in ONE launch (Wq/Wk/Wv stacked into Wqkv)
  CvtArgs ca;
  ca.x = x; ca.wq = Wq; ca.wk = Wk; ca.wv = Wv; ca.wo = Wo; ca.w1 = W1; ca.w2 = W2;
  ca.xb = xb; ca.wqd = Wqkv; ca.wkd = Wqkv + 1024 * 1024; ca.wvd = Wqkv + 2048 * 1024;
  ca.wod = Wob; ca.w1d = W1b; ca.w2d = W2b;
  k_convall<<<12288, 256, 0, stream>>>(ca);

  // 2. fused QKV projection: cols 0-1023 -> Qb, 1024-2047 -> Kb, 2048-3071 -> Vt^T
  k_gemm_bt<0,3,128><<<dim3(24, 32), 256, 0, stream>>>(xb, Wqkv, nullptr, Qb,
                                                       4096, 3072, 1024, 1024, Kb, Vtb);

  // 3. fused attention, split-KV (z = 2 halves), 4 blocks/CU, then combine
  k_attn<<<dim3(64, 8, 2), 256, 0, stream>>>(Qb, Kb, Vtb, Wm, Cm, bw, bc, Obuf, Lsb);
  k_comb<<<4096, 256, 0, stream>>>(Obuf, Lsb, Obuf);

  // 4. output projection (f32 out + bias) — BM=64 tile: grid 512 = 2 blocks/CU
  k_gemm_bt<0,0,64><<<dim3(8, 64), 256, 0, stream>>>(Obuf, Wob, bo, tmp, 4096, 1024, 1024, 1024);

  // 5. LN1: x1 = LN(x + attn_out)
  k_ln<<<4096, 256, 0, stream>>>(x, tmp, g1, be1, x1f, x1b);

  // 6. FF1 with ReLU (bf16 out) — BM=64: grid 1024 = 4 blocks/CU
  k_gemm_bt<1,1,64><<<dim3(16, 64), 256, 0, stream>>>(x1b, W1b, b1, hb, 4096, 2048, 1024, 2048);

  // 7. FF2 (f32 out) — BM=64: grid 512 = 2 blocks/CU
  k_gemm_bt<0,0,64><<<dim3(8, 64), 256, 0, stream>>>(hb, W2b, b2, tmp, 4096, 1024, 2048, 1024);

  // 8. LN2 -> d_out
  k_ln<<<4096, 256, 0, stream>>>(x1f, tmp, g2, be2, (float*)d_out, nullptr);
}